// Round 5
// baseline (141.773 us; speedup 1.0000x reference)
//
#include <hip/hip_runtime.h>
#include <math.h>

#define NXv 128
#define NYv 128
#define NZv 128
#define NVOX (NXv * NYv * NZv)
#define NCH 7   // ceil(387/64) — max 64-wide chunks per tvals row

// One wave (64 lanes) per ray, fully de-serialized:
//   1. closed-form upper bound on finite-crossing count -> nch chunks needed
//   2. all tvals chunk loads issued back-to-back (t1 via lane shuffle)
//   3. all weights/indices computed, then ALL gathers issued back-to-back
//   4. accumulate, wave shuffle-reduce, lane 0 writes B outputs
//
// NUMERICS (hard-won, rounds 1-4): segment midpoints bounded by two adjacent
// x-plane crossings land EXACTLY on floor() discontinuities. The golden ref
// is float32 numpy with SEPARATE mul-then-add rounding. hipcc's default
// -ffp-contract=fast fuses a + tm*d into FMA -> flips knife-edge floors ->
// absmax ~18.7 (threshold 1.25). __fmul_rn/__fadd_rn are contractible inline
// ops (R2 bit-identical to R1); f64 also mismatches (R3). The asm VGPR pin
// on the product is what works (R4 passed, absmax 0.0625). Do not remove.
template <int BT>
__global__ __launch_bounds__(256) void ct_fwd(
    const float* __restrict__ vol,    // (B, NX, NY, NZ)
    const float* __restrict__ tvals,  // (R, S) sorted, +inf padded
    const float* __restrict__ Mm,     // (3,3)
    const float* __restrict__ bb,     // (3,)
    const float* __restrict__ src,    // (R,3)
    const float* __restrict__ dst,    // (R,3)
    float* __restrict__ out,          // (B, R)
    int R, int S, int B)
{
#pragma clang fp contract(off)
    const int lane = threadIdx.x & 63;
    const int wib  = threadIdx.x >> 6;
    const int r    = blockIdx.x * (blockDim.x >> 6) + wib;
    if (r >= R) return;

    // --- per-ray geometry (all lanes redundantly; broadcast loads) ---
    const float sx = src[r * 3 + 0], sy = src[r * 3 + 1], sz = src[r * 3 + 2];
    const float ex = dst[r * 3 + 0], ey = dst[r * 3 + 1], ez = dst[r * 3 + 2];
    const float M00 = Mm[0], M01 = Mm[1], M02 = Mm[2];
    const float M10 = Mm[3], M11 = Mm[4], M12 = Mm[5];
    const float M20 = Mm[6], M21 = Mm[7], M22 = Mm[8];
    const float b0 = bb[0], b1 = bb[1], b2 = bb[2];

    const float ax = M00 * sx + M01 * sy + M02 * sz + b0;
    const float ay = M10 * sx + M11 * sy + M12 * sz + b1;
    const float az = M20 * sx + M21 * sy + M22 * sz + b2;
    const float vx = ex - sx, vy = ey - sy, vz = ez - sz;
    const float dx = M00 * vx + M01 * vy + M02 * vz;
    const float dy = M10 * vx + M11 * vy + M12 * vz;
    const float dz = M20 * vx + M21 * vy + M22 * vz;
    const float raylen = sqrtf(vx * vx + vy * vy + vz * vz);

    const float INF = __builtin_inff();
    const long tbase = (long)r * S;
    const int nseg = S - 1;

    // --- closed-form upper bound on # finite t-values for this ray ---
    // crossing t=(k-0.5-a)/d in [0,1]  <=>  plane k-0.5 in [min(a,a+d),max(a,a+d)].
    // 0.02 margin absorbs all f32 rounding (max abs error ~4e-5 plane units);
    // overcount only costs an extra chunk load — never drops a real crossing.
    int nfin = 0;
    {
        const float aarr[3] = {ax, ay, az};
        const float darr[3] = {dx, dy, dz};
        const int   narr[3] = {NXv, NYv, NZv};
#pragma unroll
        for (int k = 0; k < 3; ++k) {
            const float a_ = aarr[k], d_ = darr[k];
            if (fabsf(d_) > 1e-12f) {
                const float lo = fminf(a_, a_ + d_) - 0.02f;
                const float hi = fmaxf(a_, a_ + d_) + 0.02f;
                int kmin = (int)ceilf(lo + 0.5f);  if (kmin < 0) kmin = 0;
                int kmax = (int)floorf(hi + 0.5f); if (kmax > narr[k]) kmax = narr[k];
                if (kmax >= kmin) nfin += kmax - kmin + 1;
            }
        }
    }
    int nch = (nfin + 2 + 63) >> 6;   // ceil((nfin+2)/64)
    if (nch > NCH) nch = NCH;

    // --- phase 1: all tvals loads, back-to-back ---
    float tv[NCH + 1];
#pragma unroll
    for (int c = 0; c <= NCH; ++c) tv[c] = INF;
#pragma unroll
    for (int c = 0; c < NCH; ++c) {
        const int idx = (c << 6) + lane;
        if (c < nch && idx < S) tv[c] = tvals[tbase + idx];
    }

    // --- phase 2: weights + clamped flat indices for every chunk ---
    float wgt[NCH];
    int   off[NCH];
#pragma unroll
    for (int c = 0; c < NCH; ++c) {
        const int s = (c << 6) + lane;
        const float t0 = tv[c];
        float t1 = __shfl(tv[c], (lane + 1) & 63, 64);
        const float head = __shfl(tv[c + 1], 0, 64);
        if (lane == 63) t1 = head;
        const bool valid = (s < nseg) && (t0 < INF) && (t1 < INF) && (t1 > t0);
        // tmid = 0.5*(t0+t1); pts = a + tmid*d  — separate f32 roundings, NO
        // FMA: asm pins the product in a VGPR so the backend cannot contract.
        const float tm = 0.5f * (t0 + t1);
        float mx = tm * dx; asm volatile("" : "+v"(mx));
        float my = tm * dy; asm volatile("" : "+v"(my));
        float mz = tm * dz; asm volatile("" : "+v"(mz));
        const float px = ax + mx;
        const float py = ay + my;
        const float pz = az + mz;
        // clamp BEFORE int cast: inf/NaN (invalid lanes) -> well-defined OOB
        const int ix = (int)floorf(fminf(fmaxf(px, -2.0f), 200.0f));
        const int iy = (int)floorf(fminf(fmaxf(py, -2.0f), 200.0f));
        const int iz = (int)floorf(fminf(fmaxf(pz, -2.0f), 200.0f));
        const bool inb = ((unsigned)ix < NXv) && ((unsigned)iy < NYv) && ((unsigned)iz < NZv);
        const int icx = min(max(ix, 0), NXv - 1);
        const int icy = min(max(iy, 0), NYv - 1);
        const int icz = min(max(iz, 0), NZv - 1);
        wgt[c] = (valid && inb) ? (t1 - t0) * raylen : 0.0f;
        off[c] = ((icx * NYv) + icy) * NZv + icz;
    }

    // --- phase 3: all gathers, back-to-back (chunks beyond nch skipped) ---
    float g[BT][NCH];
#pragma unroll
    for (int c = 0; c < NCH; ++c) {
#pragma unroll
        for (int b = 0; b < BT; ++b) {
            g[b][c] = (c < nch) ? vol[(long)b * NVOX + off[c]] : 0.0f;
        }
    }

    // --- phase 4: accumulate + wave reduction + write ---
#pragma unroll
    for (int b = 0; b < BT; ++b) {
        float acc = 0.0f;
#pragma unroll
        for (int c = 0; c < NCH; ++c) acc += wgt[c] * g[b][c];
#pragma unroll
        for (int o = 32; o > 0; o >>= 1) acc += __shfl_xor(acc, o, 64);
        if (lane == 0) out[(long)b * R + r] = acc;
    }
}

extern "C" void kernel_launch(void* const* d_in, const int* in_sizes, int n_in,
                              void* d_out, int out_size, void* d_ws, size_t ws_size,
                              hipStream_t stream) {
    const float* vol   = (const float*)d_in[0];
    const float* tvals = (const float*)d_in[1];
    const float* Mm    = (const float*)d_in[2];
    const float* bb    = (const float*)d_in[3];
    const float* src   = (const float*)d_in[4];
    const float* dst   = (const float*)d_in[5];
    float* out = (float*)d_out;

    const int R = in_sizes[5] / 3;          // rays
    const int S = in_sizes[1] / R;          // t-values per ray
    const int B = in_sizes[0] / NVOX;       // batch of volumes

    const int wavesPerBlock = 4;            // block = 256 threads
    const int blocks = (R + wavesPerBlock - 1) / wavesPerBlock;
    dim3 grid(blocks), block(wavesPerBlock * 64);

    if (B == 2) {
        ct_fwd<2><<<grid, block, 0, stream>>>(vol, tvals, Mm, bb, src, dst, out, R, S, B);
    } else if (B == 1) {
        ct_fwd<1><<<grid, block, 0, stream>>>(vol, tvals, Mm, bb, src, dst, out, R, S, B);
    } else if (B == 4) {
        ct_fwd<4><<<grid, block, 0, stream>>>(vol, tvals, Mm, bb, src, dst, out, R, S, B);
    } else {
        int c = 0;
        for (; c + 2 <= B; c += 2)
            ct_fwd<2><<<grid, block, 0, stream>>>(vol + (long)c * NVOX, tvals, Mm, bb,
                                                  src, dst, out + (long)c * R, R, S, B);
        for (; c < B; ++c)
            ct_fwd<1><<<grid, block, 0, stream>>>(vol + (long)c * NVOX, tvals, Mm, bb,
                                                  src, dst, out + (long)c * R, R, S, B);
    }
}

// Round 7
// 93.261 us; speedup vs baseline: 1.5202x; 1.5202x over previous
//
#include <hip/hip_runtime.h>
#include <math.h>

#define NXv 128
#define NYv 128
#define NZv 128
#define NVOX (NXv * NYv * NZv)
#define RPB  64    // rays per block (lane = ray within tile compute)
#define TSEG 63    // segments per LDS tile (loads TSEG+1 = 64 t-values/ray)

// Lane-per-ray tiled kernel.
//  * tvals bits are AUTHORITATIVE: R6 proved on-the-fly recompute differs at
//    the ulp level (XLA divide != HW IEEE div bits) and flips knife-edge
//    floors (absmax 12.6). tvals must be read from memory.
//  * R4/R5 (wave-per-ray) hit a ~130us floor: every gather was 64-way
//    cache-line divergent (segments along one ray are ~64KB apart). Here
//    lane = ray: 64 consecutive rays share u, differ only in detector v ->
//    gathers of the same segment ordinal land on adjacent z voxels (2-8
//    cache lines per wave instead of 64).
//  * tvals coalescing preserved via LDS transpose: load phase = each wave
//    reads 64 CONSECUTIVE t-values of one ray (1 cache line run); compute
//    phase reads the tile transposed. Stride 65 pad -> conflict-free.
//
// NUMERICS (hard-won, rounds 1-6): x-segment midpoints land EXACTLY on
// floor() discontinuities. Golden ref is f32 numpy, SEPARATE mul-then-add.
// hipcc contracts a+tm*d into FMA -> absmax ~18.7 (threshold 1.25); __f*_rn
// are contractible (R2 == R1 bitwise); f64 mismatches (R3); recomputed t
// mismatches (R6). The asm VGPR pin on the product tm*d is what works
// (R4/R5 passed, absmax 0.0625). Do not remove. Keep contract(off) pragma.
template <int BT>
__global__ __launch_bounds__(256) void ct_tile(
    const float* __restrict__ vol,    // (B, NX, NY, NZ)
    const float* __restrict__ tvals,  // (R, S) sorted, +inf padded
    const float* __restrict__ Mm,     // (3,3)
    const float* __restrict__ bb,     // (3,)
    const float* __restrict__ src,    // (R,3)
    const float* __restrict__ dst,    // (R,3)
    float* __restrict__ out,          // (B, R)
    int R, int S)
{
#pragma clang fp contract(off)
    __shared__ float tile[RPB][TSEG + 2];          // 64 x 65: stride 65 -> no bank conflict
    __shared__ float red[4][RPB][2];               // cross-sub reduction

    const float INF = __builtin_inff();
    const int t   = threadIdx.x;
    const int rr  = t & 63;        // compute role: ray within block
    const int sub = t >> 6;        // compute role: segment sub-range 0..3
    const int r0  = blockIdx.x * RPB;
    const int r   = r0 + rr;
    const bool active = (r < R);

    // --- per-ray geometry (verified R4/R5) ---
    float ax = 0, ay = 0, az = 0, dxx = 0, dyy = 0, dzz = 0, raylen = 0;
    if (active) {
        const float sx = src[r * 3 + 0], sy = src[r * 3 + 1], sz = src[r * 3 + 2];
        const float ex = dst[r * 3 + 0], ey = dst[r * 3 + 1], ez = dst[r * 3 + 2];
        const float M00 = Mm[0], M01 = Mm[1], M02 = Mm[2];
        const float M10 = Mm[3], M11 = Mm[4], M12 = Mm[5];
        const float M20 = Mm[6], M21 = Mm[7], M22 = Mm[8];
        ax = M00 * sx + M01 * sy + M02 * sz + bb[0];
        ay = M10 * sx + M11 * sy + M12 * sz + bb[1];
        az = M20 * sx + M21 * sy + M22 * sz + bb[2];
        const float vx = ex - sx, vy = ey - sy, vz = ez - sz;
        dxx = M00 * vx + M01 * vy + M02 * vz;
        dyy = M10 * vx + M11 * vy + M12 * vz;
        dzz = M20 * vx + M21 * vy + M22 * vz;
        raylen = sqrtf(vx * vx + vy * vy + vz * vz);
    }

    const int nseg  = S - 1;
    const int ntile = (nseg + TSEG - 1) / TSEG;
    float acc0 = 0.0f, acc1 = 0.0f;

    for (int tl = 0; tl < ntile; ++tl) {
        const int s0 = tl * TSEG;
        // --- load phase: row = 4p + sub, col = rr -> each wave reads 64
        //     consecutive t-values of one ray (coalesced). 16 passes. ---
#pragma unroll 4
        for (int p = 0; p < 16; ++p) {
            const int row  = p * 4 + sub;
            const int idx  = s0 + rr;                  // t-value index
            const int ray  = r0 + row;
            tile[row][rr] = (ray < R && idx < S) ? tvals[(long)ray * S + idx] : INF;
        }
        __syncthreads();
        // sorted + INF tail: if every ray's tile starts at INF, all later
        // tiles are INF too -> block-uniform break. (Barrier also separates
        // load from compute.)
        const int alive = __syncthreads_count(tile[rr][0] < INF);
        if (alive == 0) break;

        // --- compute phase: thread (rr, sub) owns cols [16*sub, 16*sub+16) ---
        if (active) {
            const int cend = min(16 * sub + 16, TSEG);
            for (int c = 16 * sub; c < cend; ++c) {
                const int s = s0 + c;
                if (s >= nseg) break;
                const float t0 = tile[rr][c];
                const float t1 = tile[rr][c + 1];
                if ((t0 < INF) && (t1 < INF) && (t1 > t0)) {
                    // tmid=0.5*(t0+t1); pts=a+tmid*d — separate f32 roundings,
                    // NO FMA: asm pins the product (see header comment).
                    const float tm = 0.5f * (t0 + t1);
                    float mx = tm * dxx; asm volatile("" : "+v"(mx));
                    float my = tm * dyy; asm volatile("" : "+v"(my));
                    float mz = tm * dzz; asm volatile("" : "+v"(mz));
                    const float px = ax + mx;
                    const float py = ay + my;
                    const float pz = az + mz;
                    const int ix = (int)floorf(px);
                    const int iy = (int)floorf(py);
                    const int iz = (int)floorf(pz);
                    if ((unsigned)ix < NXv && (unsigned)iy < NYv && (unsigned)iz < NZv) {
                        const float w = (t1 - t0) * raylen;
                        const int flat = ((ix * NYv) + iy) * NZv + iz;
                        acc0 += w * vol[flat];
                        if (BT > 1) acc1 += w * vol[NVOX + flat];
                    }
                }
            }
        }
        __syncthreads();   // tile consumed; safe to overwrite next iteration
    }

    // --- deterministic cross-sub reduction + coalesced write ---
    red[sub][rr][0] = acc0;
    red[sub][rr][1] = (BT > 1) ? acc1 : 0.0f;
    __syncthreads();
    if (sub == 0 && active) {
        const float s0v = red[0][rr][0] + red[1][rr][0] + red[2][rr][0] + red[3][rr][0];
        out[r] = s0v;
        if (BT > 1) {
            const float s1v = red[0][rr][1] + red[1][rr][1] + red[2][rr][1] + red[3][rr][1];
            out[R + r] = s1v;
        }
    }
}

extern "C" void kernel_launch(void* const* d_in, const int* in_sizes, int n_in,
                              void* d_out, int out_size, void* d_ws, size_t ws_size,
                              hipStream_t stream) {
    const float* vol   = (const float*)d_in[0];
    const float* tvals = (const float*)d_in[1];
    const float* Mm    = (const float*)d_in[2];
    const float* bb    = (const float*)d_in[3];
    const float* src   = (const float*)d_in[4];
    const float* dst   = (const float*)d_in[5];
    float* out = (float*)d_out;

    const int R = in_sizes[5] / 3;          // rays
    const int S = in_sizes[1] / R;          // t-values per ray
    const int B = in_sizes[0] / NVOX;       // batch of volumes

    const int blocks = (R + RPB - 1) / RPB;
    dim3 grid(blocks), block(256);

    if (B == 2) {
        ct_tile<2><<<grid, block, 0, stream>>>(vol, tvals, Mm, bb, src, dst, out, R, S);
    } else if (B == 1) {
        ct_tile<1><<<grid, block, 0, stream>>>(vol, tvals, Mm, bb, src, dst, out, R, S);
    } else {
        int c = 0;
        for (; c + 2 <= B; c += 2)
            ct_tile<2><<<grid, block, 0, stream>>>(vol + (long)c * NVOX, tvals, Mm, bb,
                                                   src, dst, out + (long)c * R, R, S);
        for (; c < B; ++c)
            ct_tile<1><<<grid, block, 0, stream>>>(vol + (long)c * NVOX, tvals, Mm, bb,
                                                   src, dst, out + (long)c * R, R, S);
    }
}

// Round 8
// 84.434 us; speedup vs baseline: 1.6791x; 1.1045x over previous
//
#include <hip/hip_runtime.h>
#include <math.h>

#define NXv 128
#define NYv 128
#define NZv 128
#define NVOX (NXv * NYv * NZv)
#define RPB  64    // rays per block (lane = ray in compute phase)
#define TSEG 63    // segments per LDS tile (loads TSEG+1 = 64 t-values/ray)

// Lane-per-ray tiled kernel with register-prefetch pipeline (R8).
//  * tvals bits are AUTHORITATIVE: R6 proved on-the-fly recompute differs at
//    the ulp level (XLA divide != HW IEEE div bits) and flips knife-edge
//    floors (absmax 12.6). tvals must be read from memory.
//  * lane = ray (R7, 142->93us): consecutive rays differ only in detector v
//    -> volume gathers land on 2-8 cache lines instead of 64 (R4/R5 floor).
//  * tvals coalescing via LDS transpose tile, stride 65 -> conflict-free.
//  * R8: next tile's 16 global loads are issued into REGISTERS before the
//    compute phase (T14 async-STAGE split) — the ds_write at the next
//    iteration's top is the only consumer, so HBM latency hides under
//    compute. Compute loop fully unrolled (INF padding makes s>=nseg
//    segments invalid naturally; no break) -> 16 gather pairs in flight.
//
// NUMERICS (hard-won, rounds 1-7): x-segment midpoints land EXACTLY on
// floor() discontinuities. Golden ref is f32 numpy, SEPARATE mul-then-add.
// hipcc contracts a+tm*d into FMA -> absmax ~18.7 (threshold 1.25); __f*_rn
// are contractible (R2 == R1 bitwise); f64 mismatches (R3); recomputed t
// mismatches (R6). The asm VGPR pin on the product tm*d is what works
// (R4/R5/R7 passed, absmax 0.0625). Do not remove. Keep contract(off).
template <int BT>
__global__ __launch_bounds__(256) void ct_pipe(
    const float* __restrict__ vol,    // (B, NX, NY, NZ)
    const float* __restrict__ tvals,  // (R, S) sorted, +inf padded
    const float* __restrict__ Mm,     // (3,3)
    const float* __restrict__ bb,     // (3,)
    const float* __restrict__ src,    // (R,3)
    const float* __restrict__ dst,    // (R,3)
    float* __restrict__ out,          // (B, R)
    int R, int S)
{
#pragma clang fp contract(off)
    __shared__ float tile[RPB][TSEG + 2];   // 64 x 65: stride 65 -> conflict-free
    __shared__ float red[4][RPB][2];        // cross-sub reduction

    const float INF = __builtin_inff();
    const int t   = threadIdx.x;
    const int rr  = t & 63;        // compute role: ray within block
    const int sub = t >> 6;        // compute role: segment sub-range 0..3
    const int r0  = blockIdx.x * RPB;
    const int r   = r0 + rr;
    const bool active = (r < R);

    // --- per-ray geometry (verified R4/R5/R7) ---
    float ax = 0, ay = 0, az = 0, dxx = 0, dyy = 0, dzz = 0, raylen = 0;
    if (active) {
        const float sx = src[r * 3 + 0], sy = src[r * 3 + 1], sz = src[r * 3 + 2];
        const float ex = dst[r * 3 + 0], ey = dst[r * 3 + 1], ez = dst[r * 3 + 2];
        const float M00 = Mm[0], M01 = Mm[1], M02 = Mm[2];
        const float M10 = Mm[3], M11 = Mm[4], M12 = Mm[5];
        const float M20 = Mm[6], M21 = Mm[7], M22 = Mm[8];
        ax = M00 * sx + M01 * sy + M02 * sz + bb[0];
        ay = M10 * sx + M11 * sy + M12 * sz + bb[1];
        az = M20 * sx + M21 * sy + M22 * sz + bb[2];
        const float vx = ex - sx, vy = ey - sy, vz = ez - sz;
        dxx = M00 * vx + M01 * vy + M02 * vz;
        dyy = M10 * vx + M11 * vy + M12 * vz;
        dzz = M20 * vx + M21 * vy + M22 * vz;
        raylen = sqrtf(vx * vx + vy * vy + vz * vz);
    }

    const int nseg  = S - 1;
    const int ntile = (nseg + TSEG - 1) / TSEG;
    float acc0 = 0.0f, acc1 = 0.0f;

    // staged registers: pf[p] = tvals[ray = r0+4p+sub][s0 + rr]
    float pf[16];
    {
        const int idx = rr;                      // tile 0: s0 = 0
#pragma unroll
        for (int p = 0; p < 16; ++p) {
            const int ray = r0 + p * 4 + sub;
            pf[p] = (ray < R && idx < S) ? tvals[(long)ray * S + idx] : INF;
        }
    }

    for (int tl = 0; tl < ntile; ++tl) {
        // --- stage-write: regs -> LDS (compiler inserts the vmcnt wait here) ---
#pragma unroll
        for (int p = 0; p < 16; ++p)
            tile[p * 4 + sub][rr] = pf[p];

        // alive predicate from the staged regs (tile-start values live in the
        // rr==0 threads): sorted + INF tail means if every ray's tile starts
        // at INF, all later tiles are INF too -> block-uniform break. The
        // syncthreads_count doubles as the write->read barrier.
        bool pred = false;
        if (rr == 0) {
#pragma unroll
            for (int p = 0; p < 16; ++p) pred |= (pf[p] < INF);
        }
        const int alive = __syncthreads_count(pred);
        if (alive == 0) break;

        // --- prefetch next tile into regs (issued; consumed next iter) ---
        if (tl + 1 < ntile) {
            const int idx = (tl + 1) * TSEG + rr;
#pragma unroll
            for (int p = 0; p < 16; ++p) {
                const int ray = r0 + p * 4 + sub;
                pf[p] = (ray < R && idx < S) ? tvals[(long)ray * S + idx] : INF;
            }
        }

        // --- compute: thread (rr,sub) owns cols [16*sub, 16*sub+16), fully
        //     unrolled; s>=nseg needs no check (INF padding -> invalid) ---
        if (active) {
#pragma unroll
            for (int j = 0; j < 16; ++j) {
                const int c = 16 * sub + j;
                if (c < TSEG) {
                    const float t0 = tile[rr][c];
                    const float t1 = tile[rr][c + 1];
                    if ((t0 < INF) && (t1 < INF) && (t1 > t0)) {
                        // tmid=0.5*(t0+t1); pts=a+tmid*d — separate f32
                        // roundings, NO FMA: asm pins the product.
                        const float tm = 0.5f * (t0 + t1);
                        float mx = tm * dxx; asm volatile("" : "+v"(mx));
                        float my = tm * dyy; asm volatile("" : "+v"(my));
                        float mz = tm * dzz; asm volatile("" : "+v"(mz));
                        const float px = ax + mx;
                        const float py = ay + my;
                        const float pz = az + mz;
                        const int ix = (int)floorf(px);
                        const int iy = (int)floorf(py);
                        const int iz = (int)floorf(pz);
                        if ((unsigned)ix < NXv && (unsigned)iy < NYv && (unsigned)iz < NZv) {
                            const float w = (t1 - t0) * raylen;
                            const int flat = ((ix * NYv) + iy) * NZv + iz;
                            acc0 += w * vol[flat];
                            if (BT > 1) acc1 += w * vol[NVOX + flat];
                        }
                    }
                }
            }
        }
        __syncthreads();   // tile consumed; next iter may overwrite
    }

    // --- deterministic cross-sub reduction + coalesced write ---
    red[sub][rr][0] = acc0;
    red[sub][rr][1] = (BT > 1) ? acc1 : 0.0f;
    __syncthreads();
    if (sub == 0 && active) {
        const float s0v = red[0][rr][0] + red[1][rr][0] + red[2][rr][0] + red[3][rr][0];
        out[r] = s0v;
        if (BT > 1) {
            const float s1v = red[0][rr][1] + red[1][rr][1] + red[2][rr][1] + red[3][rr][1];
            out[R + r] = s1v;
        }
    }
}

extern "C" void kernel_launch(void* const* d_in, const int* in_sizes, int n_in,
                              void* d_out, int out_size, void* d_ws, size_t ws_size,
                              hipStream_t stream) {
    const float* vol   = (const float*)d_in[0];
    const float* tvals = (const float*)d_in[1];
    const float* Mm    = (const float*)d_in[2];
    const float* bb    = (const float*)d_in[3];
    const float* src   = (const float*)d_in[4];
    const float* dst   = (const float*)d_in[5];
    float* out = (float*)d_out;

    const int R = in_sizes[5] / 3;          // rays
    const int S = in_sizes[1] / R;          // t-values per ray
    const int B = in_sizes[0] / NVOX;       // batch of volumes

    const int blocks = (R + RPB - 1) / RPB;
    dim3 grid(blocks), block(256);

    if (B == 2) {
        ct_pipe<2><<<grid, block, 0, stream>>>(vol, tvals, Mm, bb, src, dst, out, R, S);
    } else if (B == 1) {
        ct_pipe<1><<<grid, block, 0, stream>>>(vol, tvals, Mm, bb, src, dst, out, R, S);
    } else {
        int c = 0;
        for (; c + 2 <= B; c += 2)
            ct_pipe<2><<<grid, block, 0, stream>>>(vol + (long)c * NVOX, tvals, Mm, bb,
                                                   src, dst, out + (long)c * R, R, S);
        for (; c < B; ++c)
            ct_pipe<1><<<grid, block, 0, stream>>>(vol + (long)c * NVOX, tvals, Mm, bb,
                                                   src, dst, out + (long)c * R, R, S);
    }
}